// Round 13
// baseline (17735.335 us; speedup 1.0000x reference)
//
#include <hip/hip_runtime.h>
#include <hip/hip_bf16.h>

// TimeGAN generator: 3-layer GRU (H=256) + feedback MLP, B=2048, T=256.
// Round 13: R11 numerics (bf16 h, passing) + XCD-local DATA path. R11's
// cost: sc0sc1 gathers bypass L2 -> 16x IC re-fetch of each group's h
// (~3.2 TB/s fabric demand). Fix (fast mode, co-XCD verified): stores sc0
// (dirty in shared L2), R11's proven atomic barrier, then an agent-ACQUIRE
// fence (buffer_inv: kills stale L1, preserves dirty L2 = the fresh data)
// before sc0 gathers served from the local L2. R9/R10 lesson honored: no
// plain-load polling anywhere; the only new op is a fence (cannot hang).
// Slow mode = R11 IC path verbatim. Release fence at kernel end (replay).

typedef __attribute__((ext_vector_type(8))) short short8;   // 8 x bf16
typedef __attribute__((ext_vector_type(4))) float f32x4;

#define TT   256
#define NTHR 512
#define NBLK 256

// packed-weight fragment bases (in 64-lane-frag units; elements = frag*8)
#define FB_WI0  0        // [768 x  64], KT=2
#define FB_WH0  6144     // [768 x 256], KT=8
#define FB_WI1  30720
#define FB_WH1  55296
#define FB_WI2  79872
#define FB_WH2  104448
#define FB_W1   129024   // [256 x 256]
#define FB_W2   137216   // [ 64 x 256]
#define TOTAL_FRAGS 139264

// d_ws layout (bytes)
#define OFF_FLAGS 2228224u               // 16 KB flag region
#define OFF_H0    (OFF_FLAGS + 16384u)   // [2048][256] bf16 = 1 MB
#define OFF_H1    (OFF_H0 + 1048576u)
#define OFF_H2    (OFF_H1 + 1048576u)
#define OFF_A1    (OFF_H2 + 1048576u)    // [2048][256] bf16
#define OFF_Y     (OFF_A1 + 1048576u)    // [256 blocks][128][64] bf16 = 4 MB
// flag region (u32 index):
//   [gg*64 + p]          p=0..3  FAST slots (exclusive 256B line per group)
//   [1024 + gg*8 + p]    p=0..3  IC slots for slow mode
//   [1280 + gg*16 + q]   q=0..1  init IC-barrier slots
//   [1792 + bid]                 per-block XCC id

// LDS weight-frag segment bases (1KB frags)
#define WH0_F 0
#define WI1_F 24
#define WH1_F 48
#define WI2_F 72
#define WH2_F 96
#define W2_F  120   // 32 frags
#define XW_F  152   // 6 frags -> 158 total = 161,792 B

__device__ __forceinline__ short bf16_rne(float v) {
  union { float f; unsigned u; } c; c.f = v;
  unsigned u = c.u;
  u += 0x7FFFu + ((u >> 16) & 1u);
  return (short)(u >> 16);
}
__device__ __forceinline__ float fast_sigmoid(float x) {
  return 1.0f / (1.0f + __expf(-x));
}
__device__ __forceinline__ float fast_tanh(float x) {
  return 1.0f - 2.0f / (__expf(2.0f * x) + 1.0f);
}

__device__ __forceinline__ void gll(const short* src, short* ldst) {
  __builtin_amdgcn_global_load_lds(
      (const __attribute__((address_space(1))) void*)src,
      (__attribute__((address_space(3))) void*)ldst, 16, 0, 0);
}
__device__ __forceinline__ void vm0() {
  asm volatile("s_waitcnt vmcnt(0)" ::: "memory");
  __builtin_amdgcn_sched_barrier(0);
}

// ---- coherence-templated data primitives ----
// FAST: sc0 store (write-back, dirty in the group's shared L2) + sc0 gather
//       (L2 hit; preceded by acquire-fence that invalidated stale L1).
// SLOW: R8/R11-proven IC semantics (sc0 sc1).
template<bool FAST>
__device__ __forceinline__ void gstore_f(short* g, short v) {
  if constexpr (FAST)
    asm volatile("global_store_short %0, %1, off sc0" :: "v"(g), "v"(v) : "memory");
  else
    asm volatile("global_store_short %0, %1, off sc0 sc1" :: "v"(g), "v"(v) : "memory");
}
template<bool FAST>
__device__ __forceinline__ void gather8_f(const short* base, short8 (&f)[8]) {
  if constexpr (FAST)
    asm volatile(
        "global_load_dwordx4 %0, %8, off sc0\n\t"
        "global_load_dwordx4 %1, %8, off offset:64 sc0\n\t"
        "global_load_dwordx4 %2, %8, off offset:128 sc0\n\t"
        "global_load_dwordx4 %3, %8, off offset:192 sc0\n\t"
        "global_load_dwordx4 %4, %8, off offset:256 sc0\n\t"
        "global_load_dwordx4 %5, %8, off offset:320 sc0\n\t"
        "global_load_dwordx4 %6, %8, off offset:384 sc0\n\t"
        "global_load_dwordx4 %7, %8, off offset:448 sc0\n\t"
        "s_waitcnt vmcnt(0)"
        : "=&v"(f[0]), "=&v"(f[1]), "=&v"(f[2]), "=&v"(f[3]),
          "=&v"(f[4]), "=&v"(f[5]), "=&v"(f[6]), "=&v"(f[7])
        : "v"(base) : "memory");
  else
    asm volatile(
        "global_load_dwordx4 %0, %8, off sc0 sc1\n\t"
        "global_load_dwordx4 %1, %8, off offset:64 sc0 sc1\n\t"
        "global_load_dwordx4 %2, %8, off offset:128 sc0 sc1\n\t"
        "global_load_dwordx4 %3, %8, off offset:192 sc0 sc1\n\t"
        "global_load_dwordx4 %4, %8, off offset:256 sc0 sc1\n\t"
        "global_load_dwordx4 %5, %8, off offset:320 sc0 sc1\n\t"
        "global_load_dwordx4 %6, %8, off offset:384 sc0 sc1\n\t"
        "global_load_dwordx4 %7, %8, off offset:448 sc0 sc1\n\t"
        "s_waitcnt vmcnt(0)"
        : "=&v"(f[0]), "=&v"(f[1]), "=&v"(f[2]), "=&v"(f[3]),
          "=&v"(f[4]), "=&v"(f[5]), "=&v"(f[6]), "=&v"(f[7])
        : "v"(base) : "memory");
}

__device__ __forceinline__ void gather2_l2(const short* base, short8& a, short8& b) {
  asm volatile(
      "global_load_dwordx4 %0, %2, off sc0\n\t"
      "global_load_dwordx4 %1, %2, off offset:64 sc0\n\t"
      "s_waitcnt vmcnt(0)"
      : "=&v"(a), "=&v"(b) : "v"(base) : "memory");
}
__device__ __forceinline__ void flag_add_ic(unsigned* f) {
  unsigned one = 1u;
  asm volatile("global_atomic_add %0, %1, off sc1" :: "v"(f), "v"(one) : "memory");
}
__device__ __forceinline__ unsigned flag_read_ic(unsigned* f) {
  unsigned v;
  asm volatile("global_load_dword %0, %1, off sc0 sc1\n\ts_waitcnt vmcnt(0)"
               : "=&v"(v) : "v"(f) : "memory");
  return v;
}
__device__ __forceinline__ void group_sync_ic(unsigned* flag, unsigned target) {
  vm0();
  __syncthreads();
  if (threadIdx.x == 0) {
    flag_add_ic(flag);
    while (flag_read_ic(flag) < target) __builtin_amdgcn_s_sleep(1);
  }
  __syncthreads();
}
// fast barrier: atomics only (atomics bypass L1 -- R11-proven)
__device__ __forceinline__ void flag_add_l2(unsigned* f) {
  unsigned one = 1u;
  asm volatile("global_atomic_add %0, %1, off" :: "v"(f), "v"(one) : "memory");
}
__device__ __forceinline__ unsigned flag_rmwread_l2(unsigned* f) {
  unsigned v; unsigned zero = 0u;
  asm volatile("global_atomic_add %0, %1, %2, off sc0\n\ts_waitcnt vmcnt(0)"
               : "=&v"(v) : "v"(f), "v"(zero) : "memory");
  return v;
}
__device__ __forceinline__ void group_sync_fast(unsigned* flag, unsigned base,
                                                unsigned delta) {
  vm0();
  __syncthreads();
  if (threadIdx.x == 0) {
    flag_add_l2(flag);
    while (flag_rmwread_l2(flag) - base < delta) __builtin_amdgcn_s_sleep(1);
  }
  __syncthreads();
}

struct CB4 { float brz, bzz, bin, bhn; };
__device__ __forceinline__ CB4 make_cb4(const float* bi, const float* bh, int col) {
  CB4 cb;
  cb.brz = bi[col] + bh[col];
  cb.bzz = bi[256 + col] + bh[256 + col];
  cb.bin = bi[512 + col];
  cb.bhn = bh[512 + col];
  return cb;
}

__global__ void pack_weights(const float* __restrict__ Wi0, const float* __restrict__ Wh0,
                             const float* __restrict__ Wih12, const float* __restrict__ Whh12,
                             const float* __restrict__ W1, const float* __restrict__ W2,
                             short* __restrict__ outp)
{
  int f = blockIdx.x * blockDim.x + threadIdx.x;
  if (f >= TOTAL_FRAGS) return;
  const float* src; int K; int rel;
  if (f < FB_WH0)        { src = Wi0;            K = 64;  rel = f; }
  else if (f < FB_WI1)   { src = Wh0;            K = 256; rel = f - FB_WH0; }
  else if (f < FB_WH1)   { src = Wih12;          K = 256; rel = f - FB_WI1; }
  else if (f < FB_WI2)   { src = Whh12;          K = 256; rel = f - FB_WH1; }
  else if (f < FB_WH2)   { src = Wih12 + 196608; K = 256; rel = f - FB_WI2; }
  else if (f < FB_W1)    { src = Whh12 + 196608; K = 256; rel = f - FB_WH2; }
  else if (f < FB_W2)    { src = W1;             K = 256; rel = f - FB_W1; }
  else                   { src = W2;             K = 256; rel = f - FB_W2; }
  int lane = rel & 63;
  int q = rel >> 6;
  int KT = K >> 5;
  int kt = q % KT;
  int nt = q / KT;
  int n  = nt * 16 + (lane & 15);
  int k0 = kt * 32 + (lane >> 4) * 8;
  short8 v;
#pragma unroll
  for (int e = 0; e < 8; ++e) v[e] = bf16_rne(src[(size_t)n * K + k0 + e]);
  *(short8*)(outp + (size_t)f * 8) = v;
}

__global__ void zero_flags(unsigned* f) {
  int i = threadIdx.x;
#pragma unroll
  for (int k = 0; k < 4; ++k) f[i + 1024 * k] = 0u;
}

#define MFMA(a, b, acc) __builtin_amdgcn_mfma_f32_16x16x32_bf16((a), (b), (acc), 0, 0, 0)
#define LDSF(idx) (*(const short8*)(wlds + (idx) * 512 + lane * 8))

#define GATE_UPDATE(agi, agh, cb, hm, hg)                                    \
  _Pragma("unroll") for (int j = 0; j < 4; ++j) {                            \
    float r_ = fast_sigmoid(agi[0][j] + agh[0][j] + cb.brz);                 \
    float z_ = fast_sigmoid(agi[1][j] + agh[1][j] + cb.bzz);                 \
    float n_ = fast_tanh(agi[2][j] + cb.bin + r_ * (agh[2][j] + cb.bhn));    \
    float h_ = n_ + z_ * (hm[j] - n_);                                       \
    hm[j] = h_;                                                              \
    gstore_f<FAST>(hg + (size_t)(grow0 + lhi * 4 + j) * 256 + col,           \
                   bf16_rne(h_));                                            \
  }

#define BARRIER(p)                                                            \
  do {                                                                        \
    if constexpr (FAST) {                                                     \
      group_sync_fast(fsl + (p), bs[p], 16u * (t + 1));                       \
      __builtin_amdgcn_fence(__ATOMIC_ACQUIRE, "agent");  /* inv stale L1 */  \
    } else {                                                                  \
      group_sync_ic(isl + (p), 16u * (t + 1));                                \
    }                                                                         \
  } while (0)

template<bool FAST>
__device__ void mainloop(
    const short* wlds,
    short* h0g, short* h1g, short* h2g, short* a1g, short* ybb,
    float* __restrict__ out,
    unsigned* fsl, unsigned* isl, const unsigned* bs,
    short8 (&xf)[2], short8 (&h0f)[8], short8 (&h1f)[8], short8 (&h2f)[8],
    short8 (&w1f)[8],
    float (&hm0)[4], float (&hm1)[4], float (&hm2)[4],
    const CB4 cb0, const CB4 cb1, const CB4 cb2,
    float bm1, const float (&bm2v)[4],
    int grow0, int col, int rowoff, int lane, int l15, int lhi, int w, int m)
{
  const f32x4 z4 = {0.f, 0.f, 0.f, 0.f};

#pragma unroll 1
  for (unsigned t = 0; t < TT; ++t) {
    // ===== P0: cell 0 =====
    {
      f32x4 agi[3] = {z4, z4, z4}, agh[3] = {z4, z4, z4};
#pragma unroll
      for (int g = 0; g < 3; ++g) {
        agi[g] = MFMA(xf[0], LDSF(XW_F + g * 2 + 0), agi[g]);
        agi[g] = MFMA(xf[1], LDSF(XW_F + g * 2 + 1), agi[g]);
      }
#pragma unroll
      for (int kt = 0; kt < 8; ++kt)
#pragma unroll
        for (int g = 0; g < 3; ++g)
          agh[g] = MFMA(h0f[kt], LDSF(WH0_F + g * 8 + kt), agh[g]);
      GATE_UPDATE(agi, agh, cb0, hm0, h0g)
    }
    BARRIER(0);
    gather8_f<FAST>(h0g + rowoff, h0f);

    // ===== P1: cell 1 =====
    {
      f32x4 agi[3] = {z4, z4, z4}, agh[3] = {z4, z4, z4};
#pragma unroll
      for (int kt = 0; kt < 8; ++kt)
#pragma unroll
        for (int g = 0; g < 3; ++g) {
          agi[g] = MFMA(h0f[kt], LDSF(WI1_F + g * 8 + kt), agi[g]);
          agh[g] = MFMA(h1f[kt], LDSF(WH1_F + g * 8 + kt), agh[g]);
        }
      GATE_UPDATE(agi, agh, cb1, hm1, h1g)
    }
    BARRIER(1);
    gather8_f<FAST>(h1g + rowoff, h1f);

    // ===== P2: cell 2 =====
    {
      f32x4 agi[3] = {z4, z4, z4}, agh[3] = {z4, z4, z4};
#pragma unroll
      for (int kt = 0; kt < 8; ++kt)
#pragma unroll
        for (int g = 0; g < 3; ++g) {
          agi[g] = MFMA(h1f[kt], LDSF(WI2_F + g * 8 + kt), agi[g]);
          agh[g] = MFMA(h2f[kt], LDSF(WH2_F + g * 8 + kt), agh[g]);
        }
      GATE_UPDATE(agi, agh, cb2, hm2, h2g)
    }
    BARRIER(2);
    gather8_f<FAST>(h2g + rowoff, h2f);

    // ===== P3: MLP1 (sharded cols) =====
    {
      f32x4 am = z4;
#pragma unroll
      for (int kt = 0; kt < 8; ++kt) am = MFMA(h2f[kt], w1f[kt], am);
#pragma unroll
      for (int j = 0; j < 4; ++j) {
        float v = fmaxf(am[j] + bm1, 0.f);
        gstore_f<FAST>(a1g + (size_t)(grow0 + lhi * 4 + j) * 256 + col, bf16_rne(v));
      }
    }
    BARRIER(3);
    short8 af[8];
    gather8_f<FAST>(a1g + rowoff, af);

    // ===== P4: MLP2 replicated (own rows); y bounce -> x(t+1) =====
#pragma unroll
    for (int nt = 0; nt < 4; ++nt) {
      f32x4 ay = z4;
#pragma unroll
      for (int kt = 0; kt < 8; ++kt) ay = MFMA(af[kt], LDSF(W2_F + nt * 8 + kt), ay);
#pragma unroll
      for (int j = 0; j < 4; ++j) {
        int grow = grow0 + lhi * 4 + j;
        float y = fast_tanh(ay[j] + bm2v[nt]);
        if (m == 0) out[((size_t)grow * TT + t) * 64 + nt * 16 + l15] = y;
        ybb[(w * 16 + lhi * 4 + j) * 64 + nt * 16 + l15] = bf16_rne(y);
      }
    }
    if (t < TT - 1) {
      vm0();   // own bounce-stores visible in own L2 (R8-proven)
      gather2_l2(ybb + (w * 16 + l15) * 64 + lhi * 8, xf[0], xf[1]);
    }
  }

  if constexpr (FAST) {
    // write back dirty activation lines (replay hygiene before exit)
    __builtin_amdgcn_fence(__ATOMIC_RELEASE, "agent");
  }
}

__global__ __launch_bounds__(NTHR, 2)
void timegan_shard(const float* __restrict__ noise, char* __restrict__ ws,
                   const float* __restrict__ b_ih0, const float* __restrict__ b_hh0,
                   const float* __restrict__ b_ih12, const float* __restrict__ b_hh12,
                   const float* __restrict__ b1v, const float* __restrict__ b2v,
                   float* __restrict__ out)
{
  __shared__ __align__(16) short wlds[158 * 512];    // 161,792 B
  __shared__ int fastsh;
  __shared__ unsigned bsh[4];

  const short* wpack = (const short*)ws;
  unsigned* flags = (unsigned*)(ws + OFF_FLAGS);
  short* h0g = (short*)(ws + OFF_H0);
  short* h1g = (short*)(ws + OFF_H1);
  short* h2g = (short*)(ws + OFF_H2);
  short* a1g = (short*)(ws + OFF_A1);
  short* yg  = (short*)(ws + OFF_Y);

  const int tid = threadIdx.x;
  const int lane = tid & 63, w = tid >> 6;
  const int l15 = lane & 15, lhi = lane >> 4;
  const int bid = blockIdx.x;
  const int gg = bid & 15;               // group (batch slice)
  const int m  = bid >> 4;               // member (column shard)
  const int grow0 = gg * 128 + w * 16;   // this wave's first global row
  const int col = m * 16 + l15;          // this lane's shard column
  unsigned* fsl    = flags + gg * 64;              // fast slots (own 256B line)
  unsigned* isl    = flags + 1024 + gg * 8;        // IC slots
  unsigned* initA  = flags + 1280 + gg * 16;       // init barrier slots
  unsigned* initB  = initA + 1;
  unsigned* xccids = flags + 1792;
  short* ybb = yg + (size_t)bid * 128 * 64;        // block-private bounce

  // ---- one-time: LDS weight shard (wave 0 issues the DMA) ----
  if (w == 0) {
    int dst = 0;
    const int fbs[5] = {FB_WH0, FB_WI1, FB_WH1, FB_WI2, FB_WH2};
    for (int s = 0; s < 5; ++s)
      for (int g = 0; g < 3; ++g)
        for (int kt = 0; kt < 8; ++kt) {
          gll(wpack + ((size_t)fbs[s] + (size_t)((g * 16 + m) * 8 + kt) * 64 + lane) * 8,
              wlds + dst * 512);
          ++dst;
        }
    for (int nt = 0; nt < 4; ++nt)                      // W2 (full)
      for (int kt = 0; kt < 8; ++kt) {
        gll(wpack + ((size_t)FB_W2 + (nt * 8 + kt) * 64 + lane) * 8, wlds + dst * 512);
        ++dst;
      }
    for (int g = 0; g < 3; ++g)                         // Wi0 shard
      for (int kt = 0; kt < 2; ++kt) {
        gll(wpack + ((size_t)FB_WI0 + ((g * 16 + m) * 2 + kt) * 64 + lane) * 8,
            wlds + dst * 512);
        ++dst;
      }
  }

  // ---- register weights: W1 shard (8 frags) ----
  short8 w1f[8];
#pragma unroll
  for (int kt = 0; kt < 8; ++kt)
    w1f[kt] = *(const short8*)(wpack + ((size_t)FB_W1 + (m * 8 + kt) * 64 + lane) * 8);

  // ---- x frags from noise ----
  short8 xf[2];
  {
    const float* np = noise + (size_t)(grow0 + l15) * 64;
#pragma unroll
    for (int kt = 0; kt < 2; ++kt) {
      f32x4 u0 = *(const f32x4*)(np + kt * 32 + lhi * 8);
      f32x4 u1 = *(const f32x4*)(np + kt * 32 + lhi * 8 + 4);
      short8 v;
#pragma unroll
      for (int e = 0; e < 4; ++e) { v[e] = bf16_rne(u0[e]); v[4 + e] = bf16_rne(u1[e]); }
      xf[kt] = v;
    }
  }

  // ---- biases ----
  CB4 cb0 = make_cb4(b_ih0, b_hh0, col);
  CB4 cb1 = make_cb4(b_ih12, b_hh12, col);
  CB4 cb2 = make_cb4(b_ih12 + 768, b_hh12 + 768, col);
  float bm1 = b1v[col];
  float bm2v[4];
#pragma unroll
  for (int nt = 0; nt < 4; ++nt) bm2v[nt] = b2v[nt * 16 + l15];

  // ---- persistent state ----
  short8 h0f[8], h1f[8], h2f[8];
  float hm0[4], hm1[4], hm2[4];
  {
    short8 z8 = {0, 0, 0, 0, 0, 0, 0, 0};
#pragma unroll
    for (int kt = 0; kt < 8; ++kt) { h0f[kt] = z8; h1f[kt] = z8; h2f[kt] = z8; }
#pragma unroll
    for (int j = 0; j < 4; ++j) { hm0[j] = 0.f; hm1[j] = 0.f; hm2[j] = 0.f; }
  }

  // ---- publish XCC id (IC domain, R8-proven ops) ----
  if (tid == 0) {
    unsigned xcc = 0;
    asm volatile("s_getreg_b32 %0, hwreg(HW_REG_XCC_ID)" : "=s"(xcc));
    unsigned* myid = xccids + bid;
    unsigned xv = xcc;
    asm volatile("global_store_dword %0, %1, off sc0 sc1" :: "v"(myid), "v"(xv) : "memory");
  }
  group_sync_ic(initA, 16u);   // covers weight-DMA drain + xcc publish

  // ---- verify co-XCD residency ----
  if (tid < 64) {
    unsigned* xp = xccids + gg + 16 * (lane & 15);
    unsigned xv;
    asm volatile("global_load_dword %0, %1, off sc0 sc1\n\ts_waitcnt vmcnt(0)"
                 : "=&v"(xv) : "v"(xp) : "memory");
    unsigned ref = __shfl(xv, 0);
    int ok = __all(xv == ref);
    if (lane == 0) fastsh = ok;
  }
  __syncthreads();

  // ---- snapshot fast-slot bases (replay-safe relative targets) ----
  if (tid == 0 && fastsh) {
#pragma unroll
    for (int p = 0; p < 4; ++p) bsh[p] = flag_rmwread_l2(fsl + p);
  }
  group_sync_ic(initB, 16u);

  const bool fast = fastsh != 0;
  const int rowoff = (grow0 + l15) * 256 + lhi * 8;   // gather base (shorts)

  if (fast)
    mainloop<true>(wlds, h0g, h1g, h2g, a1g, ybb, out, fsl, isl, bsh,
                   xf, h0f, h1f, h2f, w1f, hm0, hm1, hm2,
                   cb0, cb1, cb2, bm1, bm2v,
                   grow0, col, rowoff, lane, l15, lhi, w, m);
  else
    mainloop<false>(wlds, h0g, h1g, h2g, a1g, ybb, out, fsl, isl, bsh,
                    xf, h0f, h1f, h2f, w1f, hm0, hm1, hm2,
                    cb0, cb1, cb2, bm1, bm2v,
                    grow0, col, rowoff, lane, l15, lhi, w, m);
}

extern "C" void kernel_launch(void* const* d_in, const int* in_sizes, int n_in,
                              void* d_out, int out_size, void* d_ws, size_t ws_size,
                              hipStream_t stream)
{
  const float* noise  = (const float*)d_in[0];
  const float* W_ih0  = (const float*)d_in[1];
  const float* W_hh0  = (const float*)d_in[2];
  const float* b_ih0  = (const float*)d_in[3];
  const float* b_hh0  = (const float*)d_in[4];
  const float* W_ih12 = (const float*)d_in[5];
  const float* W_hh12 = (const float*)d_in[6];
  const float* b_ih12 = (const float*)d_in[7];
  const float* b_hh12 = (const float*)d_in[8];
  const float* W1     = (const float*)d_in[9];
  const float* b1     = (const float*)d_in[10];
  const float* W2     = (const float*)d_in[11];
  const float* b2     = (const float*)d_in[12];
  float* out = (float*)d_out;
  char* ws = (char*)d_ws;
  short* wpack = (short*)d_ws;

  zero_flags<<<1, 1024, 0, stream>>>((unsigned*)(ws + OFF_FLAGS));
  pack_weights<<<(TOTAL_FRAGS + 255) / 256, 256, 0, stream>>>(
      W_ih0, W_hh0, W_ih12, W_hh12, W1, W2, wpack);

  timegan_shard<<<NBLK, NTHR, 0, stream>>>(
      noise, ws, b_ih0, b_hh0, b_ih12, b_hh12, b1, b2, out);
}

// Round 14
// 5032.754 us; speedup vs baseline: 3.5240x; 3.5240x over previous
//
#include <hip/hip_runtime.h>
#include <hip/hip_bf16.h>

// TimeGAN generator: 3-layer GRU (H=256) + feedback MLP, B=2048, T=256.
// Round 14: R13 with the per-phase fence changed from compiler agent-acquire
// (emits buffer_inv sc1 = FULL L2 WALK -> R13's 17-89ms) to raw plain
// `buffer_inv` (vector-L1-only invalidate). Co-XCD fast path: sc0 stores
// dirty the shared L2 (coherence point), atomic barrier (R11-proven), then
// L1-inv kills the only hazard -- stale L1 lines from the previous step's
// gather of the same addresses (the R9/R10 freeze mechanism). Own-block
// y-bounce needs no inv (own stores update own L1). Slow mode = R11 IC
// path verbatim for non-co-XCD groups. R13 proved fast-path CORRECTNESS
// (passed, FETCH 542->173MB); this round removes its fence cost.

typedef __attribute__((ext_vector_type(8))) short short8;   // 8 x bf16
typedef __attribute__((ext_vector_type(4))) float f32x4;

#define TT   256
#define NTHR 512
#define NBLK 256

// packed-weight fragment bases (in 64-lane-frag units; elements = frag*8)
#define FB_WI0  0        // [768 x  64], KT=2
#define FB_WH0  6144     // [768 x 256], KT=8
#define FB_WI1  30720
#define FB_WH1  55296
#define FB_WI2  79872
#define FB_WH2  104448
#define FB_W1   129024   // [256 x 256]
#define FB_W2   137216   // [ 64 x 256]
#define TOTAL_FRAGS 139264

// d_ws layout (bytes)
#define OFF_FLAGS 2228224u               // 16 KB flag region
#define OFF_H0    (OFF_FLAGS + 16384u)   // [2048][256] bf16 = 1 MB
#define OFF_H1    (OFF_H0 + 1048576u)
#define OFF_H2    (OFF_H1 + 1048576u)
#define OFF_A1    (OFF_H2 + 1048576u)    // [2048][256] bf16
#define OFF_Y     (OFF_A1 + 1048576u)    // [256 blocks][128][64] bf16 = 4 MB
// flag region (u32 index):
//   [gg*64 + p]          p=0..3  FAST slots (exclusive 256B line per group)
//   [1024 + gg*8 + p]    p=0..3  IC slots for slow mode
//   [1280 + gg*16 + q]   q=0..1  init IC-barrier slots
//   [1792 + bid]                 per-block XCC id

// LDS weight-frag segment bases (1KB frags)
#define WH0_F 0
#define WI1_F 24
#define WH1_F 48
#define WI2_F 72
#define WH2_F 96
#define W2_F  120   // 32 frags
#define XW_F  152   // 6 frags -> 158 total = 161,792 B

__device__ __forceinline__ short bf16_rne(float v) {
  union { float f; unsigned u; } c; c.f = v;
  unsigned u = c.u;
  u += 0x7FFFu + ((u >> 16) & 1u);
  return (short)(u >> 16);
}
__device__ __forceinline__ float fast_sigmoid(float x) {
  return 1.0f / (1.0f + __expf(-x));
}
__device__ __forceinline__ float fast_tanh(float x) {
  return 1.0f - 2.0f / (__expf(2.0f * x) + 1.0f);
}

__device__ __forceinline__ void gll(const short* src, short* ldst) {
  __builtin_amdgcn_global_load_lds(
      (const __attribute__((address_space(1))) void*)src,
      (__attribute__((address_space(3))) void*)ldst, 16, 0, 0);
}
__device__ __forceinline__ void vm0() {
  asm volatile("s_waitcnt vmcnt(0)" ::: "memory");
  __builtin_amdgcn_sched_barrier(0);
}

// ---- coherence-templated data primitives ----
template<bool FAST>
__device__ __forceinline__ void gstore_f(short* g, short v) {
  if constexpr (FAST)
    asm volatile("global_store_short %0, %1, off sc0" :: "v"(g), "v"(v) : "memory");
  else
    asm volatile("global_store_short %0, %1, off sc0 sc1" :: "v"(g), "v"(v) : "memory");
}
template<bool FAST>
__device__ __forceinline__ void gather8_f(const short* base, short8 (&f)[8]) {
  if constexpr (FAST)
    asm volatile(
        "global_load_dwordx4 %0, %8, off sc0\n\t"
        "global_load_dwordx4 %1, %8, off offset:64 sc0\n\t"
        "global_load_dwordx4 %2, %8, off offset:128 sc0\n\t"
        "global_load_dwordx4 %3, %8, off offset:192 sc0\n\t"
        "global_load_dwordx4 %4, %8, off offset:256 sc0\n\t"
        "global_load_dwordx4 %5, %8, off offset:320 sc0\n\t"
        "global_load_dwordx4 %6, %8, off offset:384 sc0\n\t"
        "global_load_dwordx4 %7, %8, off offset:448 sc0\n\t"
        "s_waitcnt vmcnt(0)"
        : "=&v"(f[0]), "=&v"(f[1]), "=&v"(f[2]), "=&v"(f[3]),
          "=&v"(f[4]), "=&v"(f[5]), "=&v"(f[6]), "=&v"(f[7])
        : "v"(base) : "memory");
  else
    asm volatile(
        "global_load_dwordx4 %0, %8, off sc0 sc1\n\t"
        "global_load_dwordx4 %1, %8, off offset:64 sc0 sc1\n\t"
        "global_load_dwordx4 %2, %8, off offset:128 sc0 sc1\n\t"
        "global_load_dwordx4 %3, %8, off offset:192 sc0 sc1\n\t"
        "global_load_dwordx4 %4, %8, off offset:256 sc0 sc1\n\t"
        "global_load_dwordx4 %5, %8, off offset:320 sc0 sc1\n\t"
        "global_load_dwordx4 %6, %8, off offset:384 sc0 sc1\n\t"
        "global_load_dwordx4 %7, %8, off offset:448 sc0 sc1\n\t"
        "s_waitcnt vmcnt(0)"
        : "=&v"(f[0]), "=&v"(f[1]), "=&v"(f[2]), "=&v"(f[3]),
          "=&v"(f[4]), "=&v"(f[5]), "=&v"(f[6]), "=&v"(f[7])
        : "v"(base) : "memory");
}

__device__ __forceinline__ void gather2_l2(const short* base, short8& a, short8& b) {
  asm volatile(
      "global_load_dwordx4 %0, %2, off sc0\n\t"
      "global_load_dwordx4 %1, %2, off offset:64 sc0\n\t"
      "s_waitcnt vmcnt(0)"
      : "=&v"(a), "=&v"(b) : "v"(base) : "memory");
}
__device__ __forceinline__ void flag_add_ic(unsigned* f) {
  unsigned one = 1u;
  asm volatile("global_atomic_add %0, %1, off sc1" :: "v"(f), "v"(one) : "memory");
}
__device__ __forceinline__ unsigned flag_read_ic(unsigned* f) {
  unsigned v;
  asm volatile("global_load_dword %0, %1, off sc0 sc1\n\ts_waitcnt vmcnt(0)"
               : "=&v"(v) : "v"(f) : "memory");
  return v;
}
__device__ __forceinline__ void group_sync_ic(unsigned* flag, unsigned target) {
  vm0();
  __syncthreads();
  if (threadIdx.x == 0) {
    flag_add_ic(flag);
    while (flag_read_ic(flag) < target) __builtin_amdgcn_s_sleep(1);
  }
  __syncthreads();
}
// fast barrier: atomics only (R11-proven; atomics never read stale L1)
__device__ __forceinline__ void flag_add_l2(unsigned* f) {
  unsigned one = 1u;
  asm volatile("global_atomic_add %0, %1, off" :: "v"(f), "v"(one) : "memory");
}
__device__ __forceinline__ unsigned flag_rmwread_l2(unsigned* f) {
  unsigned v; unsigned zero = 0u;
  asm volatile("global_atomic_add %0, %1, %2, off sc0\n\ts_waitcnt vmcnt(0)"
               : "=&v"(v) : "v"(f), "v"(zero) : "memory");
  return v;
}
__device__ __forceinline__ void group_sync_fast(unsigned* flag, unsigned base,
                                                unsigned delta) {
  vm0();
  __syncthreads();
  if (threadIdx.x == 0) {
    flag_add_l2(flag);
    while (flag_rmwread_l2(flag) - base < delta) __builtin_amdgcn_s_sleep(1);
  }
  __syncthreads();
}

struct CB4 { float brz, bzz, bin, bhn; };
__device__ __forceinline__ CB4 make_cb4(const float* bi, const float* bh, int col) {
  CB4 cb;
  cb.brz = bi[col] + bh[col];
  cb.bzz = bi[256 + col] + bh[256 + col];
  cb.bin = bi[512 + col];
  cb.bhn = bh[512 + col];
  return cb;
}

__global__ void pack_weights(const float* __restrict__ Wi0, const float* __restrict__ Wh0,
                             const float* __restrict__ Wih12, const float* __restrict__ Whh12,
                             const float* __restrict__ W1, const float* __restrict__ W2,
                             short* __restrict__ outp)
{
  int f = blockIdx.x * blockDim.x + threadIdx.x;
  if (f >= TOTAL_FRAGS) return;
  const float* src; int K; int rel;
  if (f < FB_WH0)        { src = Wi0;            K = 64;  rel = f; }
  else if (f < FB_WI1)   { src = Wh0;            K = 256; rel = f - FB_WH0; }
  else if (f < FB_WH1)   { src = Wih12;          K = 256; rel = f - FB_WI1; }
  else if (f < FB_WI2)   { src = Whh12;          K = 256; rel = f - FB_WH1; }
  else if (f < FB_WH2)   { src = Wih12 + 196608; K = 256; rel = f - FB_WI2; }
  else if (f < FB_W1)    { src = Whh12 + 196608; K = 256; rel = f - FB_WH2; }
  else if (f < FB_W2)    { src = W1;             K = 256; rel = f - FB_W1; }
  else                   { src = W2;             K = 256; rel = f - FB_W2; }
  int lane = rel & 63;
  int q = rel >> 6;
  int KT = K >> 5;
  int kt = q % KT;
  int nt = q / KT;
  int n  = nt * 16 + (lane & 15);
  int k0 = kt * 32 + (lane >> 4) * 8;
  short8 v;
#pragma unroll
  for (int e = 0; e < 8; ++e) v[e] = bf16_rne(src[(size_t)n * K + k0 + e]);
  *(short8*)(outp + (size_t)f * 8) = v;
}

__global__ void zero_flags(unsigned* f) {
  int i = threadIdx.x;
#pragma unroll
  for (int k = 0; k < 4; ++k) f[i + 1024 * k] = 0u;
}

#define MFMA(a, b, acc) __builtin_amdgcn_mfma_f32_16x16x32_bf16((a), (b), (acc), 0, 0, 0)
#define LDSF(idx) (*(const short8*)(wlds + (idx) * 512 + lane * 8))

#define GATE_UPDATE(agi, agh, cb, hm, hg)                                    \
  _Pragma("unroll") for (int j = 0; j < 4; ++j) {                            \
    float r_ = fast_sigmoid(agi[0][j] + agh[0][j] + cb.brz);                 \
    float z_ = fast_sigmoid(agi[1][j] + agh[1][j] + cb.bzz);                 \
    float n_ = fast_tanh(agi[2][j] + cb.bin + r_ * (agh[2][j] + cb.bhn));    \
    float h_ = n_ + z_ * (hm[j] - n_);                                       \
    hm[j] = h_;                                                              \
    gstore_f<FAST>(hg + (size_t)(grow0 + lhi * 4 + j) * 256 + col,           \
                   bf16_rne(h_));                                            \
  }

// fast: atomic barrier then PLAIN buffer_inv = vector-L1-only invalidate
// (sc1 would walk L2 -- that was R13's 17-89ms). Kills stale L1 lines from
// the previous step's gather of these same addresses; L2 (the co-XCD
// coherence point) is untouched and serves the fresh dirty lines.
#define BARRIER(p)                                                            \
  do {                                                                        \
    if constexpr (FAST) {                                                     \
      group_sync_fast(fsl + (p), bs[p], 16u * (t + 1));                       \
      asm volatile("buffer_inv" ::: "memory");                                \
      __builtin_amdgcn_sched_barrier(0);                                      \
    } else {                                                                  \
      group_sync_ic(isl + (p), 16u * (t + 1));                                \
    }                                                                         \
  } while (0)

template<bool FAST>
__device__ void mainloop(
    const short* wlds,
    short* h0g, short* h1g, short* h2g, short* a1g, short* ybb,
    float* __restrict__ out,
    unsigned* fsl, unsigned* isl, const unsigned* bs,
    short8 (&xf)[2], short8 (&h0f)[8], short8 (&h1f)[8], short8 (&h2f)[8],
    short8 (&w1f)[8],
    float (&hm0)[4], float (&hm1)[4], float (&hm2)[4],
    const CB4 cb0, const CB4 cb1, const CB4 cb2,
    float bm1, const float (&bm2v)[4],
    int grow0, int col, int rowoff, int lane, int l15, int lhi, int w, int m)
{
  const f32x4 z4 = {0.f, 0.f, 0.f, 0.f};

#pragma unroll 1
  for (unsigned t = 0; t < TT; ++t) {
    // ===== P0: cell 0 =====
    {
      f32x4 agi[3] = {z4, z4, z4}, agh[3] = {z4, z4, z4};
#pragma unroll
      for (int g = 0; g < 3; ++g) {
        agi[g] = MFMA(xf[0], LDSF(XW_F + g * 2 + 0), agi[g]);
        agi[g] = MFMA(xf[1], LDSF(XW_F + g * 2 + 1), agi[g]);
      }
#pragma unroll
      for (int kt = 0; kt < 8; ++kt)
#pragma unroll
        for (int g = 0; g < 3; ++g)
          agh[g] = MFMA(h0f[kt], LDSF(WH0_F + g * 8 + kt), agh[g]);
      GATE_UPDATE(agi, agh, cb0, hm0, h0g)
    }
    BARRIER(0);
    gather8_f<FAST>(h0g + rowoff, h0f);

    // ===== P1: cell 1 =====
    {
      f32x4 agi[3] = {z4, z4, z4}, agh[3] = {z4, z4, z4};
#pragma unroll
      for (int kt = 0; kt < 8; ++kt)
#pragma unroll
        for (int g = 0; g < 3; ++g) {
          agi[g] = MFMA(h0f[kt], LDSF(WI1_F + g * 8 + kt), agi[g]);
          agh[g] = MFMA(h1f[kt], LDSF(WH1_F + g * 8 + kt), agh[g]);
        }
      GATE_UPDATE(agi, agh, cb1, hm1, h1g)
    }
    BARRIER(1);
    gather8_f<FAST>(h1g + rowoff, h1f);

    // ===== P2: cell 2 =====
    {
      f32x4 agi[3] = {z4, z4, z4}, agh[3] = {z4, z4, z4};
#pragma unroll
      for (int kt = 0; kt < 8; ++kt)
#pragma unroll
        for (int g = 0; g < 3; ++g) {
          agi[g] = MFMA(h1f[kt], LDSF(WI2_F + g * 8 + kt), agi[g]);
          agh[g] = MFMA(h2f[kt], LDSF(WH2_F + g * 8 + kt), agh[g]);
        }
      GATE_UPDATE(agi, agh, cb2, hm2, h2g)
    }
    BARRIER(2);
    gather8_f<FAST>(h2g + rowoff, h2f);

    // ===== P3: MLP1 (sharded cols) =====
    {
      f32x4 am = z4;
#pragma unroll
      for (int kt = 0; kt < 8; ++kt) am = MFMA(h2f[kt], w1f[kt], am);
#pragma unroll
      for (int j = 0; j < 4; ++j) {
        float v = fmaxf(am[j] + bm1, 0.f);
        gstore_f<FAST>(a1g + (size_t)(grow0 + lhi * 4 + j) * 256 + col, bf16_rne(v));
      }
    }
    BARRIER(3);
    short8 af[8];
    gather8_f<FAST>(a1g + rowoff, af);

    // ===== P4: MLP2 replicated (own rows); y bounce -> x(t+1) =====
#pragma unroll
    for (int nt = 0; nt < 4; ++nt) {
      f32x4 ay = z4;
#pragma unroll
      for (int kt = 0; kt < 8; ++kt) ay = MFMA(af[kt], LDSF(W2_F + nt * 8 + kt), ay);
#pragma unroll
      for (int j = 0; j < 4; ++j) {
        int grow = grow0 + lhi * 4 + j;
        float y = fast_tanh(ay[j] + bm2v[nt]);
        if (m == 0) out[((size_t)grow * TT + t) * 64 + nt * 16 + l15] = y;
        ybb[(w * 16 + lhi * 4 + j) * 64 + nt * 16 + l15] = bf16_rne(y);
      }
    }
    if (t < TT - 1) {
      vm0();   // own bounce-stores: own L1 updated by own stores (safe)
      gather2_l2(ybb + (w * 16 + l15) * 64 + lhi * 8, xf[0], xf[1]);
    }
  }

  if constexpr (FAST) {
    // one-time release: write back dirty L2 lines for replay hygiene
    __builtin_amdgcn_fence(__ATOMIC_RELEASE, "agent");
  }
}

__global__ __launch_bounds__(NTHR, 2)
void timegan_shard(const float* __restrict__ noise, char* __restrict__ ws,
                   const float* __restrict__ b_ih0, const float* __restrict__ b_hh0,
                   const float* __restrict__ b_ih12, const float* __restrict__ b_hh12,
                   const float* __restrict__ b1v, const float* __restrict__ b2v,
                   float* __restrict__ out)
{
  __shared__ __align__(16) short wlds[158 * 512];    // 161,792 B
  __shared__ int fastsh;
  __shared__ unsigned bsh[4];

  const short* wpack = (const short*)ws;
  unsigned* flags = (unsigned*)(ws + OFF_FLAGS);
  short* h0g = (short*)(ws + OFF_H0);
  short* h1g = (short*)(ws + OFF_H1);
  short* h2g = (short*)(ws + OFF_H2);
  short* a1g = (short*)(ws + OFF_A1);
  short* yg  = (short*)(ws + OFF_Y);

  const int tid = threadIdx.x;
  const int lane = tid & 63, w = tid >> 6;
  const int l15 = lane & 15, lhi = lane >> 4;
  const int bid = blockIdx.x;
  const int gg = bid & 15;               // group (batch slice)
  const int m  = bid >> 4;               // member (column shard)
  const int grow0 = gg * 128 + w * 16;   // this wave's first global row
  const int col = m * 16 + l15;          // this lane's shard column
  unsigned* fsl    = flags + gg * 64;              // fast slots (own 256B line)
  unsigned* isl    = flags + 1024 + gg * 8;        // IC slots
  unsigned* initA  = flags + 1280 + gg * 16;       // init barrier slots
  unsigned* initB  = initA + 1;
  unsigned* xccids = flags + 1792;
  short* ybb = yg + (size_t)bid * 128 * 64;        // block-private bounce

  // ---- one-time: LDS weight shard (wave 0 issues the DMA) ----
  if (w == 0) {
    int dst = 0;
    const int fbs[5] = {FB_WH0, FB_WI1, FB_WH1, FB_WI2, FB_WH2};
    for (int s = 0; s < 5; ++s)
      for (int g = 0; g < 3; ++g)
        for (int kt = 0; kt < 8; ++kt) {
          gll(wpack + ((size_t)fbs[s] + (size_t)((g * 16 + m) * 8 + kt) * 64 + lane) * 8,
              wlds + dst * 512);
          ++dst;
        }
    for (int nt = 0; nt < 4; ++nt)                      // W2 (full)
      for (int kt = 0; kt < 8; ++kt) {
        gll(wpack + ((size_t)FB_W2 + (nt * 8 + kt) * 64 + lane) * 8, wlds + dst * 512);
        ++dst;
      }
    for (int g = 0; g < 3; ++g)                         // Wi0 shard
      for (int kt = 0; kt < 2; ++kt) {
        gll(wpack + ((size_t)FB_WI0 + ((g * 16 + m) * 2 + kt) * 64 + lane) * 8,
            wlds + dst * 512);
        ++dst;
      }
  }

  // ---- register weights: W1 shard (8 frags) ----
  short8 w1f[8];
#pragma unroll
  for (int kt = 0; kt < 8; ++kt)
    w1f[kt] = *(const short8*)(wpack + ((size_t)FB_W1 + (m * 8 + kt) * 64 + lane) * 8);

  // ---- x frags from noise ----
  short8 xf[2];
  {
    const float* np = noise + (size_t)(grow0 + l15) * 64;
#pragma unroll
    for (int kt = 0; kt < 2; ++kt) {
      f32x4 u0 = *(const f32x4*)(np + kt * 32 + lhi * 8);
      f32x4 u1 = *(const f32x4*)(np + kt * 32 + lhi * 8 + 4);
      short8 v;
#pragma unroll
      for (int e = 0; e < 4; ++e) { v[e] = bf16_rne(u0[e]); v[4 + e] = bf16_rne(u1[e]); }
      xf[kt] = v;
    }
  }

  // ---- biases ----
  CB4 cb0 = make_cb4(b_ih0, b_hh0, col);
  CB4 cb1 = make_cb4(b_ih12, b_hh12, col);
  CB4 cb2 = make_cb4(b_ih12 + 768, b_hh12 + 768, col);
  float bm1 = b1v[col];
  float bm2v[4];
#pragma unroll
  for (int nt = 0; nt < 4; ++nt) bm2v[nt] = b2v[nt * 16 + l15];

  // ---- persistent state ----
  short8 h0f[8], h1f[8], h2f[8];
  float hm0[4], hm1[4], hm2[4];
  {
    short8 z8 = {0, 0, 0, 0, 0, 0, 0, 0};
#pragma unroll
    for (int kt = 0; kt < 8; ++kt) { h0f[kt] = z8; h1f[kt] = z8; h2f[kt] = z8; }
#pragma unroll
    for (int j = 0; j < 4; ++j) { hm0[j] = 0.f; hm1[j] = 0.f; hm2[j] = 0.f; }
  }

  // ---- publish XCC id (IC domain, R8-proven ops) ----
  if (tid == 0) {
    unsigned xcc = 0;
    asm volatile("s_getreg_b32 %0, hwreg(HW_REG_XCC_ID)" : "=s"(xcc));
    unsigned* myid = xccids + bid;
    unsigned xv = xcc;
    asm volatile("global_store_dword %0, %1, off sc0 sc1" :: "v"(myid), "v"(xv) : "memory");
  }
  group_sync_ic(initA, 16u);   // covers weight-DMA drain + xcc publish

  // ---- verify co-XCD residency ----
  if (tid < 64) {
    unsigned* xp = xccids + gg + 16 * (lane & 15);
    unsigned xv;
    asm volatile("global_load_dword %0, %1, off sc0 sc1\n\ts_waitcnt vmcnt(0)"
                 : "=&v"(xv) : "v"(xp) : "memory");
    unsigned ref = __shfl(xv, 0);
    int ok = __all(xv == ref);
    if (lane == 0) fastsh = ok;
  }
  __syncthreads();

  // ---- snapshot fast-slot bases (replay-safe relative targets) ----
  if (tid == 0 && fastsh) {
#pragma unroll
    for (int p = 0; p < 4; ++p) bsh[p] = flag_rmwread_l2(fsl + p);
  }
  group_sync_ic(initB, 16u);

  const bool fast = fastsh != 0;
  const int rowoff = (grow0 + l15) * 256 + lhi * 8;   // gather base (shorts)

  if (fast)
    mainloop<true>(wlds, h0g, h1g, h2g, a1g, ybb, out, fsl, isl, bsh,
                   xf, h0f, h1f, h2f, w1f, hm0, hm1, hm2,
                   cb0, cb1, cb2, bm1, bm2v,
                   grow0, col, rowoff, lane, l15, lhi, w, m);
  else
    mainloop<false>(wlds, h0g, h1g, h2g, a1g, ybb, out, fsl, isl, bsh,
                    xf, h0f, h1f, h2f, w1f, hm0, hm1, hm2,
                    cb0, cb1, cb2, bm1, bm2v,
                    grow0, col, rowoff, lane, l15, lhi, w, m);
}

extern "C" void kernel_launch(void* const* d_in, const int* in_sizes, int n_in,
                              void* d_out, int out_size, void* d_ws, size_t ws_size,
                              hipStream_t stream)
{
  const float* noise  = (const float*)d_in[0];
  const float* W_ih0  = (const float*)d_in[1];
  const float* W_hh0  = (const float*)d_in[2];
  const float* b_ih0  = (const float*)d_in[3];
  const float* b_hh0  = (const float*)d_in[4];
  const float* W_ih12 = (const float*)d_in[5];
  const float* W_hh12 = (const float*)d_in[6];
  const float* b_ih12 = (const float*)d_in[7];
  const float* b_hh12 = (const float*)d_in[8];
  const float* W1     = (const float*)d_in[9];
  const float* b1     = (const float*)d_in[10];
  const float* W2     = (const float*)d_in[11];
  const float* b2     = (const float*)d_in[12];
  float* out = (float*)d_out;
  char* ws = (char*)d_ws;
  short* wpack = (short*)d_ws;

  zero_flags<<<1, 1024, 0, stream>>>((unsigned*)(ws + OFF_FLAGS));
  pack_weights<<<(TOTAL_FRAGS + 255) / 256, 256, 0, stream>>>(
      W_ih0, W_hh0, W_ih12, W_hh12, W1, W2, wpack);

  timegan_shard<<<NBLK, NTHR, 0, stream>>>(
      noise, ws, b_ih0, b_hh0, b_ih12, b_hh12, b1, b2, out);
}